// Round 1
// baseline (261.711 us; speedup 1.0000x reference)
//
#include <hip/hip_runtime.h>
#include <hip/hip_bf16.h>

typedef __bf16 bf16;
typedef __bf16 bf16x4 __attribute__((ext_vector_type(4)));
typedef __bf16 bf16x8 __attribute__((ext_vector_type(8)));
typedef float f32x4 __attribute__((ext_vector_type(4)));

#define HID 4096
#define NQH 32
#define NKVH 8
#define HD 128
#define MAXLEN 8192
#define PAST 4096
#define SCALE 0.08838834764831845f
#define NEGBIG (-30000.0f)

// GEMM K-split config
#define KS 8          // K splits (blocks per N-tile)
#define KPB 512       // K elements per block
// attention chunking
#define ACH 64        // keys per past chunk
#define NCH 65        // 64 past chunks + 1 new chunk

__device__ __forceinline__ f32x4 mfma16(bf16x8 a, bf16x8 b, f32x4 c) {
  return __builtin_amdgcn_mfma_f32_16x16x32_bf16(a, b, c, 0, 0, 0);
}

__device__ __forceinline__ bf16x8 pack8(f32x4 a, f32x4 b) {
  bf16x8 r;
  r[0] = (bf16)a[0]; r[1] = (bf16)a[1]; r[2] = (bf16)a[2]; r[3] = (bf16)a[3];
  r[4] = (bf16)b[0]; r[5] = (bf16)b[1]; r[6] = (bf16)b[2]; r[7] = (bf16)b[3];
  return r;
}

__device__ __forceinline__ bf16x8 load8f(const float* p) {
  const f32x4* q = (const f32x4*)p;
  return pack8(q[0], q[1]);
}

// fragment-major index: element (k, m) of a 16-row operand.
__device__ __forceinline__ int fmidx(int k, int m) {
  return ((k >> 3) * 16 + m) * 8 + (k & 7);
}

// ---------------- zero the qkv fp32 accumulator (atomicAdd target) ----------------
__global__ __launch_bounds__(256) void zeroq_kernel(float* __restrict__ qa) {
  f32x4 z = {0.f, 0.f, 0.f, 0.f};
  *(f32x4*)(qa + (size_t)(blockIdx.x * 256 + threadIdx.x) * 4) = z;
}

// ---------------- GEMM: direct global->reg->MFMA, fp32 atomic epilogue ----------------
// C[m][n] += A[16][K] . W[n][K]^T over one K-slice of 512.
// A: fp32 (x, L2-resident) or bf16 row-major [16][HID].
// No W LDS staging: W has zero reuse (M=16), B-fragments load straight from global.
template <int NT, int OSTR, bool AF32>
__global__ __launch_bounds__(256) void gemm16_kernel(const void* __restrict__ aptr,
                                                     const float* __restrict__ w,
                                                     float* __restrict__ oacc) {
  int tid = threadIdx.x, lane = tid & 63, wv = tid >> 6;
  int l15 = lane & 15, quad = lane >> 4;
  int nt = blockIdx.x % NT, kq = blockIdx.x / NT;
  __shared__ __align__(16) float red[4][64][4];

  int kbase = kq * KPB + wv * 128 + quad * 8;

  // B fragments: lane l15 = W row (n), 16B contiguous in K. Scattered 16B/lane
  // across 16 rows; every fetched line is fully consumed by this block.
  const float* wb = w + (size_t)(nt * 16 + l15) * HID + kbase;
  f32x4 w0[4], w1[4];
#pragma unroll
  for (int kk = 0; kk < 4; ++kk) {
    w0[kk] = *(const f32x4*)(wb + kk * 32);
    w1[kk] = *(const f32x4*)(wb + kk * 32 + 4);
  }

  // A fragments: lane l15 = token row m, same K window. L2-resident (256KB/128KB).
  bf16x8 af[4];
  if constexpr (AF32) {
    const float* ab = (const float*)aptr + (size_t)l15 * HID + kbase;
#pragma unroll
    for (int kk = 0; kk < 4; ++kk) af[kk] = load8f(ab + kk * 32);
  } else {
    const bf16* ab = (const bf16*)aptr + (size_t)l15 * HID + kbase;
#pragma unroll
    for (int kk = 0; kk < 4; ++kk) af[kk] = *(const bf16x8*)(ab + kk * 32);
  }

  f32x4 acc = {0.f, 0.f, 0.f, 0.f};
#pragma unroll
  for (int kk = 0; kk < 4; ++kk)
    acc = mfma16(af[kk], pack8(w0[kk], w1[kk]), acc);

  // cross-wave reduce (4 K-subchunks), then one fp32 atomicAdd per output elem
  *(f32x4*)(&red[wv][lane][0]) = acc;
  __syncthreads();
  if (wv == 0) {
#pragma unroll
    for (int r = 0; r < 4; ++r) {
      float v = red[0][lane][r] + red[1][lane][r] + red[2][lane][r] + red[3][lane][r];
      atomicAdd(oacc + (size_t)(quad * 4 + r) * OSTR + nt * 16 + l15, v);
    }
  }
}

// ---------------- qkv finish: RoPE -> Qfrag/Kfrag bf16, Vnew bf16 ----------------
// qa layout: [m][6144] fp32 (m-major) -> reads are contiguous in n.
__global__ __launch_bounds__(256) void qkv_finish_kernel(const float* __restrict__ qa,
                                                         bf16* __restrict__ Qf,
                                                         bf16* __restrict__ Kf,
                                                         bf16* __restrict__ Vn) {
  int id = blockIdx.x * 256 + threadIdx.x;   // 57344 total
  if (id < 32768) {           // Q: 32 heads x 16 m x 64 pairs
    int qh = id >> 10, m = (id >> 6) & 15, j = id & 63;
    float e = qa[(size_t)m * 6144 + qh * 128 + j];
    float o = qa[(size_t)m * 6144 + qh * 128 + 64 + j];
    float sn, co;
    __sincosf((float)m * (float)j * (1.0f / 64.0f), &sn, &co);
    Qf[qh * 2048 + fmidx(j, m)] = (bf16)((e * co - o * sn) * SCALE);
    Qf[qh * 2048 + fmidx(j + 64, m)] = (bf16)((e * sn + o * co) * SCALE);
  } else if (id < 40960) {    // K: 8 heads x 16 m x 64 pairs
    int v = id - 32768;
    int kvh = v >> 10, m = (v >> 6) & 15, j = v & 63;
    float e = qa[(size_t)m * 6144 + 4096 + kvh * 128 + j];
    float o = qa[(size_t)m * 6144 + 4096 + kvh * 128 + 64 + j];
    float sn, co;
    __sincosf((float)m * (float)j * (1.0f / 64.0f), &sn, &co);
    Kf[kvh * 2048 + fmidx(j, m)] = (bf16)(e * co - o * sn);
    Kf[kvh * 2048 + fmidx(j + 64, m)] = (bf16)(e * sn + o * co);
  } else if (id < 57344) {    // V: 8 heads x 16 m x 128 d
    int v = id - 40960;
    int kvh = v >> 11, m = (v >> 7) & 15, d = v & 127;
    Vn[kvh * 2048 + m * 128 + d] = (bf16)qa[(size_t)m * 6144 + 5120 + kvh * 128 + d];
  }
}

// ---------------- attention partials (unchanged this round) ----------------
template <bool NEW>
__device__ void attn_body(int kvh, int c,
                          const float* __restrict__ ck, const float* __restrict__ cv,
                          const bf16* __restrict__ Qf, const bf16* __restrict__ Kf,
                          const bf16* __restrict__ Vn,
                          bf16* __restrict__ Opart, float* __restrict__ ml,
                          bf16* Kt, bf16* Vt, bf16* Pl) {
  int tid = threadIdx.x, lane = tid & 63, wv = tid >> 6;
  int l15 = lane & 15, quad = lane >> 4;
  int qh = kvh * 4 + wv;
  int cs = c * ACH;

  // ---- staging ----
  if (!NEW) {
    {
      int kr = tid >> 5;
      int kc4 = tid & 31;
      f32x4 kst[8];
#pragma unroll
      for (int it = 0; it < 8; ++it)
        kst[it] = *(const f32x4*)(ck + ((size_t)(kvh * MAXLEN + cs + it * 8 + kr)) * HD + kc4 * 4);
      int key = tid & 63, dg = tid >> 6;
      f32x4 vst[8];
#pragma unroll
      for (int q4 = 0; q4 < 8; ++q4)
        vst[q4] = *(const f32x4*)(cv + ((size_t)(kvh * MAXLEN + cs + key)) * HD + dg * 32 + q4 * 4);
#pragma unroll
      for (int it = 0; it < 8; ++it) {
        bf16x4 t;
        t[0] = (bf16)kst[it][0]; t[1] = (bf16)kst[it][1];
        t[2] = (bf16)kst[it][2]; t[3] = (bf16)kst[it][3];
        *(bf16x4*)(Kt + (it * 8 + kr) * 136 + kc4 * 4) = t;
      }
#pragma unroll
      for (int q4 = 0; q4 < 8; ++q4)
#pragma unroll
        for (int i = 0; i < 4; ++i)
          Vt[(dg * 32 + q4 * 4 + i) * 72 + key] = (bf16)vst[q4][i];
    }
  } else {
    int key = tid >> 4, dg8 = tid & 15;
    bf16x8 v = *(const bf16x8*)(Vn + kvh * 2048 + key * 128 + dg8 * 8);
#pragma unroll
    for (int i = 0; i < 8; ++i) {
      Vt[(dg8 * 8 + i) * 72 + key] = v[i];
      Vt[(dg8 * 8 + i) * 72 + 16 + key] = (bf16)0.f;
    }
  }
  __syncthreads();

  bf16x8 af[4];
#pragma unroll
  for (int kk = 0; kk < 4; ++kk)
    af[kk] = *(const bf16x8*)(Qf + qh * 2048 + ((kk * 4 + quad) * 16 + l15) * 8);

  constexpr int NT = NEW ? 1 : 4;
  f32x4 sc[NT];
  if (!NEW) {
#pragma unroll
    for (int nt = 0; nt < NT; ++nt) {
      f32x4 acc = {0.f, 0.f, 0.f, 0.f};
#pragma unroll
      for (int kk = 0; kk < 4; ++kk) {
        bf16x8 b = *(const bf16x8*)(Kt + (nt * 16 + l15) * 136 + kk * 32 + quad * 8);
        acc = mfma16(af[kk], b, acc);
      }
      sc[nt] = acc;
    }
  } else {
    f32x4 acc = {0.f, 0.f, 0.f, 0.f};
#pragma unroll
    for (int kk = 0; kk < 4; ++kk) {
      bf16x8 b = *(const bf16x8*)(Kf + kvh * 2048 + ((kk * 4 + quad) * 16 + l15) * 8);
      acc = mfma16(af[kk], b, acc);
    }
#pragma unroll
    for (int r = 0; r < 4; ++r)
      if (l15 > quad * 4 + r) acc[r] = NEGBIG;
    sc[0] = acc;
  }

  float mx[4], sm[4];
#pragma unroll
  for (int r = 0; r < 4; ++r) {
    float v = sc[0][r];
#pragma unroll
    for (int nt = 1; nt < NT; ++nt) v = fmaxf(v, sc[nt][r]);
    v = fmaxf(v, __shfl_xor(v, 1));
    v = fmaxf(v, __shfl_xor(v, 2));
    v = fmaxf(v, __shfl_xor(v, 4));
    v = fmaxf(v, __shfl_xor(v, 8));
    mx[r] = v;
  }
#pragma unroll
  for (int nt = 0; nt < NT; ++nt)
#pragma unroll
    for (int r = 0; r < 4; ++r) sc[nt][r] = __expf(sc[nt][r] - mx[r]);
#pragma unroll
  for (int r = 0; r < 4; ++r) {
    float v = 0.f;
#pragma unroll
    for (int nt = 0; nt < NT; ++nt) v += sc[nt][r];
    v += __shfl_xor(v, 1);
    v += __shfl_xor(v, 2);
    v += __shfl_xor(v, 4);
    v += __shfl_xor(v, 8);
    sm[r] = v;
  }

  bf16* Pw = Pl + wv * 16 * 72;
#pragma unroll
  for (int nt = 0; nt < NT; ++nt)
#pragma unroll
    for (int r = 0; r < 4; ++r)
      Pw[(quad * 4 + r) * 72 + nt * 16 + l15] = (bf16)sc[nt][r];
  if (NEW) {
#pragma unroll
    for (int r = 0; r < 4; ++r)
      Pw[(quad * 4 + r) * 72 + 16 + l15] = (bf16)0.f;
  }
  __syncthreads();

  constexpr int KI = NEW ? 1 : 2;
  int rowblk = ((kvh * NCH + c) * 4 + wv) * 16;
  bf16* ob = Opart + (size_t)rowblk * 128;
#pragma unroll
  for (int nt2 = 0; nt2 < 8; ++nt2) {
    f32x4 acc = {0.f, 0.f, 0.f, 0.f};
#pragma unroll
    for (int kk = 0; kk < KI; ++kk) {
      bf16x8 a = *(const bf16x8*)(Pw + l15 * 72 + kk * 32 + quad * 8);
      bf16x8 b = *(const bf16x8*)(Vt + (nt2 * 16 + l15) * 72 + kk * 32 + quad * 8);
      acc = mfma16(a, b, acc);
    }
#pragma unroll
    for (int r = 0; r < 4; ++r)
      ob[(quad * 4 + r) * 128 + nt2 * 16 + l15] = (bf16)acc[r];
  }
  if (l15 == 0) {
#pragma unroll
    for (int r = 0; r < 4; ++r) {
      ml[(size_t)(rowblk + quad * 4 + r) * 2] = mx[r];
      ml[(size_t)(rowblk + quad * 4 + r) * 2 + 1] = sm[r];
    }
  }
}

__global__ __launch_bounds__(256) void attn_kernel(const float* __restrict__ ck,
                                                   const float* __restrict__ cv,
                                                   const bf16* __restrict__ Qf,
                                                   const bf16* __restrict__ Kf,
                                                   const bf16* __restrict__ Vn,
                                                   bf16* __restrict__ Opart,
                                                   float* __restrict__ ml) {
  __shared__ __align__(16) bf16 KtL[64 * 136];
  __shared__ __align__(16) bf16 VtL[128 * 72];
  __shared__ __align__(16) bf16 PL[4 * 16 * 72];
  int c = blockIdx.x % NCH;
  int kvh = blockIdx.x / NCH;
  if (c == NCH - 1)
    attn_body<true>(kvh, c, ck, cv, Qf, Kf, Vn, Opart, ml, KtL, VtL, PL);
  else
    attn_body<false>(kvh, c, ck, cv, Qf, Kf, Vn, Opart, ml, KtL, VtL, PL);
}

// ---------------- combine: 512 blocks, 4 waves split the 65 chunks ----------------
// Each block owns one (qh, srow). Wave wv handles chunks wv, wv+4, ... (<=17 each),
// then a two-level online-softmax merge across waves via LDS. Also zeroes `out`
// (gemm2's atomic target) while it's on the GPU anyway.
__global__ __launch_bounds__(256) void combine_kernel(const bf16* __restrict__ Opart,
                                                      const float* __restrict__ ml,
                                                      bf16* __restrict__ attrm,
                                                      float* __restrict__ out) {
  int tid = threadIdx.x, lane = tid & 63, wv = tid >> 6;
  int qh = blockIdx.x >> 4, srow = blockIdx.x & 15;
  int kvh = qh >> 2, lw = qh & 3;
  size_t rowblk0 = ((size_t)(kvh * NCH) * 4 + lw) * 16 + srow;   // chunk stride = 64 rows

  // zero out[16][4096] fp32: 512 blocks x 32 f32x4 = 16384
  if (tid < 32) {
    f32x4 z = {0.f, 0.f, 0.f, 0.f};
    *(f32x4*)(out + (size_t)(blockIdx.x * 32 + tid) * 4) = z;
  }

  // pass 1: wave-local max over its chunks
  float mw = NEGBIG;
  for (int c = wv; c < NCH; c += 4)
    mw = fmaxf(mw, ml[(rowblk0 + (size_t)c * 64) * 2]);

  // pass 2: weighted accumulate (lane owns dims lane and lane+64)
  float a0 = 0.f, a1 = 0.f, Lw = 0.f;
  for (int c = wv; c < NCH; c += 4) {
    const float* mlc = ml + (rowblk0 + (size_t)c * 64) * 2;
    float wc = __expf(mlc[0] - mw);
    Lw += wc * mlc[1];
    const bf16* oc = Opart + (rowblk0 + (size_t)c * 64) * 128;
    a0 += wc * (float)oc[lane];
    a1 += wc * (float)oc[64 + lane];
  }

  __shared__ float sm_m[4], sm_l[4];
  __shared__ float sm_a[4][128];
  if (lane == 0) { sm_m[wv] = mw; sm_l[wv] = Lw; }
  sm_a[wv][lane] = a0;
  sm_a[wv][64 + lane] = a1;
  __syncthreads();

  if (wv == 0) {
    float M = fmaxf(fmaxf(sm_m[0], sm_m[1]), fmaxf(sm_m[2], sm_m[3]));
    float s0 = __expf(sm_m[0] - M), s1 = __expf(sm_m[1] - M);
    float s2 = __expf(sm_m[2] - M), s3 = __expf(sm_m[3] - M);
    float L = s0 * sm_l[0] + s1 * sm_l[1] + s2 * sm_l[2] + s3 * sm_l[3];
    float inv = 1.f / L;
    float A0 = s0 * sm_a[0][lane] + s1 * sm_a[1][lane] + s2 * sm_a[2][lane] + s3 * sm_a[3][lane];
    float A1 = s0 * sm_a[0][64 + lane] + s1 * sm_a[1][64 + lane] +
               s2 * sm_a[2][64 + lane] + s3 * sm_a[3][64 + lane];
    attrm[(size_t)srow * HID + qh * 128 + lane] = (bf16)(A0 * inv);
    attrm[(size_t)srow * HID + qh * 128 + 64 + lane] = (bf16)(A1 * inv);
  }
}

extern "C" void kernel_launch(void* const* d_in, const int* in_sizes, int n_in,
                              void* d_out, int out_size, void* d_ws, size_t ws_size,
                              hipStream_t stream) {
  const float* x       = (const float*)d_in[0];
  const float* w_qkv   = (const float*)d_in[1];
  const float* w_out   = (const float*)d_in[2];
  const float* cache_k = (const float*)d_in[3];
  const float* cache_v = (const float*)d_in[4];
  float* out = (float*)d_out;

  // ws layout (bytes, all 256B-aligned by construction)
  char* p = (char*)d_ws;
  float* qkvacc = (float*)p;             p += (size_t)16 * 6144 * 4;           // 384 KB  [m][6144]
  bf16*  Qf     = (bf16*)p;              p += (size_t)NQH * 2048 * 2;          // 128 KB
  bf16*  Kf     = (bf16*)p;              p += (size_t)NKVH * 2048 * 2;         // 32 KB
  bf16*  Vn     = (bf16*)p;              p += (size_t)NKVH * 2048 * 2;         // 32 KB
  bf16*  Opart  = (bf16*)p;              p += (size_t)NKVH * NCH * 4 * 16 * 128 * 2;  // 8.5 MB
  float* ml     = (float*)p;             p += (size_t)NKVH * NCH * 4 * 16 * 2 * 4;    // 266 KB
  bf16*  attrm  = (bf16*)p;              p += (size_t)16 * HID * 2;            // 128 KB  row-major

  hipLaunchKernelGGL(zeroq_kernel, dim3(96), dim3(256), 0, stream, qkvacc);
  hipLaunchKernelGGL((gemm16_kernel<384, 6144, true>), dim3(384 * KS), dim3(256), 0, stream,
                     (const void*)x, w_qkv, qkvacc);
  hipLaunchKernelGGL(qkv_finish_kernel, dim3(224), dim3(256), 0, stream, qkvacc, Qf, Kf, Vn);
  hipLaunchKernelGGL(attn_kernel, dim3(NKVH * NCH), dim3(256), 0, stream,
                     cache_k, cache_v, Qf, Kf, Vn, Opart, ml);
  hipLaunchKernelGGL(combine_kernel, dim3(512), dim3(256), 0, stream, Opart, ml, attrm, out);
  hipLaunchKernelGGL((gemm16_kernel<256, 4096, false>), dim3(256 * KS), dim3(256), 0, stream,
                     (const void*)attrm, w_out, out);
}